// Round 18
// baseline (274.547 us; speedup 1.0000x reference)
//
#include <hip/hip_runtime.h>

// Problem constants (from reference)
#define KA 240000
#define NI 4
#define MG 50
#define NSEL 256u
#define CAPL 4096          // boundary-bin member cap per group (expect ~260)
#define APT 8              // anchors per thread
#define BPI 118            // ceil(240000 / (256*8))
#define GRID1 (BPI * NI)   // 472 blocks (co-resident: << capacity)

typedef unsigned int u32;

// ws layout (u32 units):
//   hist [0,16384)  8 groups x 2048 bins (key>>21)
//   meta [16384,16416)  us[8] | R[8] | done[8] | cnt[8]
//   tick [16416,16418)  last-block tickets for D1, D2
//   list [16418, +8*CAPL*2)  (key, idx) boundary-bin members
//   flags after list: u32 per 8 anchors (4-bit flags), 30000 words
#define METAO 16384
#define TICKO (METAO + 32)
#define LISTO (TICKO + 2)
#define FLAGO (LISTO + 8 * CAPL * 2)
#define ONE_F 0x3F800000u

// monotone f32 -> u32 sortkey (order-preserving for all finite floats)
static __device__ __forceinline__ u32 sortkey32(float f) {
    u32 b = __float_as_uint(f);
    return (b & 0x80000000u) ? ~b : (b | 0x80000000u);
}
static __device__ __forceinline__ u32 aload(const u32* p) {
    return __hip_atomic_load(p, __ATOMIC_ACQUIRE, __HIP_MEMORY_SCOPE_AGENT);
}
static __device__ __forceinline__ void astore(u32* p, u32 v) {
    __hip_atomic_store(p, v, __ATOMIC_RELEASE, __HIP_MEMORY_SCOPE_AGENT);
}
// agent-scope atomic dword store: scattered 1.0 patches from different XCDs can
// share a 64B line without lost updates.
static __device__ __forceinline__ void patch1(u32* p) {
    __hip_atomic_store(p, ONE_F, __ATOMIC_RELAXED, __HIP_MEMORY_SCOPE_AGENT);
}

// ---------------- D1: zero + IoU/argmax + targets + hist + last-block boundary ----------------
// Inputs f32 (established R5-R13). No-spin last-block: every block tickets once at
// the end; the block drawing GRID1-1 (all other blocks' device-scope atomics are
// complete & visible) computes the 8 group boundaries. Nobody waits.
extern "C" __global__ void __launch_bounds__(256, 4)
AnchorTargetLayer_48052094107725_kernel(
    const float4* __restrict__ anchors, const float* __restrict__ scores,
    const float4* __restrict__ gtb, const int* __restrict__ glab,
    float* __restrict__ out, u32* __restrict__ ws) {
#pragma clang fp contract(off)
    __shared__ float4 gA[MG];
    __shared__ float gare[MG];
    __shared__ int glb[MG];
    __shared__ u32 lh[2048];        // packed hist: pos low16 | neg high16
    __shared__ u32 cs[256];
    __shared__ u32 s_tick;
    const int bx = blockIdx.x;
    const int tid = threadIdx.x;
    const int n = bx / BPI;
    const int kb = bx - n * BPI;

    if (tid < 35) {
        const int i = bx * 35 + tid;          // 472*35 = 16520 >= 16418
        if (i < LISTO) atomicExch(&ws[i], 0u);
    }
    for (int i = tid; i < 2048; i += 256) lh[i] = 0;
    if (tid < MG) {
        const float4 G = gtb[n * MG + tid];
        gA[tid] = G;
        gare[tid] = (G.z - G.x) * (G.w - G.y);   // same f32 ops as reference
        glb[tid] = glab[n * MG + tid];
    }
    __syncthreads();

    const int k0 = (kb * 256 + tid) * APT;    // 8 consecutive anchors (KA%8==0)
    if (k0 < KA) {
        float ax0[APT], ay0[APT], ax2[APT], ay2[APT];
        #pragma unroll
        for (int j = 0; j < APT; ++j) {
            const float4 A = anchors[k0 + j];
            ax0[j] = A.x; ay0[j] = A.y; ax2[j] = A.z; ay2[j] = A.w;
        }
        float aaw[APT], aah[APT], aar[APT], bst[APT];
        int bix[APT];
        #pragma unroll
        for (int j = 0; j < APT; ++j) {
            aaw[j] = ax2[j] - ax0[j];
            aah[j] = ay2[j] - ay0[j];
            aar[j] = aaw[j] * aah[j];
            bst[j] = -1.0f;
            bix[j] = 0;
        }
        for (int m = 0; m < MG; ++m) {
            const float4 Ga = gA[m];
            const float gaA = gare[m];
            #pragma unroll
            for (int j = 0; j < APT; ++j) {
                const float wa = fmaxf(fminf(ax2[j], Ga.z) - fmaxf(ax0[j], Ga.x), 0.0f);
                const float ha = fmaxf(fminf(ay2[j], Ga.w) - fmaxf(ay0[j], Ga.y), 0.0f);
                const float ia = wa * ha;
                const float qa = ia / (((aar[j] + gaA) - ia) + 1e-8f);  // IEEE f32 div
                if (qa > bst[j]) { bst[j] = qa; bix[j] = m; }   // strict >: first idx
            }
        }

        const int nk = n * KA + k0;
        const float4 sa = ((const float4*)scores)[nk >> 2];
        const float4 sb = ((const float4*)scores)[(nk >> 2) + 1];
        const float scv[APT] = {sa.x, sa.y, sa.z, sa.w, sb.x, sb.y, sb.z, sb.w};

        float clsv[APT];
        u32 flagpack = 0;
        const size_t NK = (size_t)NI * KA;
        float4* regp = ((float4*)(out + NK)) + nk;
        #pragma unroll
        for (int j = 0; j < APT; ++j) {
            const bool pos = bst[j] >= 0.7f;
            const bool neg = bst[j] < 0.3f;
            clsv[j] = pos ? (float)glb[bix[j]] : 0.0f;
            float4 rv = make_float4(0.0f, 0.0f, 0.0f, 0.0f);
            if (pos) {
                const float4 Gm = gA[bix[j]];
                const float gw = Gm.z - Gm.x, gh = Gm.w - Gm.y;
                const float gcx = Gm.x + 0.5f * gw, gcy = Gm.y + 0.5f * gh;
                const float acx = ax0[j] + 0.5f * aaw[j], acy = ay0[j] + 0.5f * aah[j];
                rv.x = (gcx - acx) / aaw[j];
                rv.y = (gcy - acy) / aah[j];
                rv.z = logf(gw / aaw[j]);
                rv.w = logf(gh / aah[j]);
            }
            regp[j] = rv;
            const u32 fl = pos ? 1u : (neg ? 2u : 0u);
            flagpack |= fl << (4 * j);
            if (fl) atomicAdd(&lh[sortkey32(scv[j]) >> 21], fl == 2u ? 0x10000u : 1u);
        }
        const size_t NK4 = NK / 4;
        const int t4 = nk >> 2;
        ((float4*)out)[t4] = make_float4(clsv[0], clsv[1], clsv[2], clsv[3]);
        ((float4*)out)[t4 + 1] = make_float4(clsv[4], clsv[5], clsv[6], clsv[7]);
        const float4 z4 = make_float4(0.0f, 0.0f, 0.0f, 0.0f);
        ((float4*)out)[5 * NK4 + t4] = z4;       // weights prewrite (0.0)
        ((float4*)out)[5 * NK4 + t4 + 1] = z4;
        ((float4*)out)[6 * NK4 + t4] = z4;
        ((float4*)out)[6 * NK4 + t4 + 1] = z4;
        ws[FLAGO + (nk / APT)] = flagpack;
    }
    __syncthreads();
    {   // merge packed LDS histogram into per-group global hist (device atomics)
        const int gp = 2 * n;
        for (int i = tid; i < 2048; i += 256) {
            const u32 c = lh[i];
            if (c & 0xFFFFu) atomicAdd(&ws[gp * 2048 + i], c & 0xFFFFu);
            if (c >> 16)     atomicAdd(&ws[(gp + 1) * 2048 + i], c >> 16);
        }
    }
    // ----- no-spin last-block ticket -----
    __threadfence();
    if (tid == 0) s_tick = atomicAdd(&ws[TICKO], 1u);
    __syncthreads();
    if (s_tick == (u32)(GRID1 - 1)) {
        u32* meta = ws + METAO;
        for (int g = 0; g < 8; ++g) {            // boundary scan per group
            u32 loc[8];
            u32 s = 0;
            const int base = g * 2048 + tid * 8;
            #pragma unroll
            for (int j = 0; j < 8; ++j) { loc[j] = aload(&ws[base + j]); s += loc[j]; }
            cs[tid] = s;
            __syncthreads();
            for (int d = 1; d < 256; d <<= 1) {
                const u32 add = (tid + d < 256) ? cs[tid + d] : 0u;
                __syncthreads();
                cs[tid] += add;
                __syncthreads();
            }
            if (tid == 0) meta[16 + g] = (cs[0] < NSEL) ? 1u : 0u;  // done: take all
            u32 run = (tid < 255) ? cs[tid + 1] : 0u;
            #pragma unroll
            for (int j = 7; j >= 0; --j) {
                const u32 Sj = run + loc[j];
                if (Sj >= NSEL && run < NSEL) {
                    meta[g] = (u32)(tid * 8 + j);   // boundary 11-bit prefix
                    meta[8 + g] = NSEL - run;       // R1: slots within bin
                }
                run = Sj;
            }
            __syncthreads();
        }
    }
}

// ---------------- D2: sparse weight patches + tie collection + last-block refine ----------------
__global__ void __launch_bounds__(256, 4) kP(const float* __restrict__ scores,
                                             u32* __restrict__ ws,
                                             float* __restrict__ out) {
    __shared__ u32 s_meta[32];
    __shared__ u32 h2[1024];
    __shared__ u32 cs[256];
    __shared__ u32 tk[256], ti[256];
    __shared__ u32 s_usb, s_R2, s_tc, s_tick;
    u32* meta = ws + METAO;
    u32* list = ws + LISTO;
    const int bx = blockIdx.x, tid = threadIdx.x;
    const int n = bx / BPI, kb = bx - n * BPI;
    if (tid < 32) s_meta[tid] = meta[tid];       // D1 output: visible (new dispatch)
    __syncthreads();

    const int k0 = (kb * 256 + tid) * APT;
    const size_t NK = (size_t)NI * KA;
    u32* o32 = (u32*)out;
    if (k0 < KA) {
        const int nk = n * KA + k0;
        const u32 fw = ws[FLAGO + (nk / APT)];
        if (fw) {
            const float4 sa = ((const float4*)scores)[nk >> 2];
            const float4 sb = ((const float4*)scores)[(nk >> 2) + 1];
            const float scv[APT] = {sa.x, sa.y, sa.z, sa.w, sb.x, sb.y, sb.z, sb.w};
            #pragma unroll
            for (int j = 0; j < APT; ++j) {
                const u32 f = (fw >> (4 * j)) & 15u;
                if (!f) continue;
                const int g = 2 * n + ((f == 2u) ? 1 : 0);
                bool in = false;
                if (s_meta[16 + g]) {
                    in = true;                    // group < 256 members: take all
                } else {
                    const u32 key = sortkey32(scv[j]);
                    const u32 p11 = key >> 21;
                    if (p11 > s_meta[g]) {
                        in = true;
                    } else if (p11 == s_meta[g]) {
                        // boundary-bin member: defer verdict to last-block refine
                        const u32 p = atomicAdd(&meta[24 + g], 1u);
                        if (p < CAPL) {
                            astore(&list[(g * CAPL + p) * 2], key);
                            astore(&list[(g * CAPL + p) * 2 + 1], (u32)(k0 + j));
                        }
                    }
                }
                if (in) {
                    patch1(&o32[5 * NK + nk + j]);               // cls_weights = 1.0
                    if (f == 1u) patch1(&o32[6 * NK + nk + j]);  // reg_weights = 1.0
                }
            }
        }
    }
    // ----- no-spin last-block ticket: refinement for all 8 groups -----
    __threadfence();
    if (tid == 0) s_tick = atomicAdd(&ws[TICKO + 1], 1u);
    __syncthreads();
    if (s_tick != (u32)(GRID1 - 1)) return;
    for (int g = 0; g < 8; ++g) {
        if (s_meta[16 + g]) continue;            // take-all group: already patched
        u32 c = aload(&meta[24 + g]);
        if (c > CAPL) c = CAPL;
        const u32 R1 = s_meta[8 + g];
        for (u32 i = tid; i < 1024; i += 256) h2[i] = 0;
        if (tid == 0) s_tc = 0;
        __syncthreads();
        for (u32 j = tid; j < c; j += 256)
            atomicAdd(&h2[(aload(&list[(g * CAPL + j) * 2]) >> 11) & 1023u], 1u);
        __syncthreads();
        u32 loc[4];
        u32 s = 0;
        #pragma unroll
        for (int j = 0; j < 4; ++j) { loc[j] = h2[tid * 4 + j]; s += loc[j]; }
        cs[tid] = s;
        __syncthreads();
        for (int d = 1; d < 256; d <<= 1) {
            const u32 add = (tid + d < 256) ? cs[tid + d] : 0u;
            __syncthreads();
            cs[tid] += add;
            __syncthreads();
        }
        u32 run = (tid < 255) ? cs[tid + 1] : 0u;
        #pragma unroll
        for (int j = 3; j >= 0; --j) {
            const u32 Sj = run + loc[j];
            if (Sj >= R1 && run < R1) { s_usb = (u32)(tid * 4 + j); s_R2 = R1 - run; }
            run = Sj;
        }
        __syncthreads();
        const u32 usb = s_usb, R2 = s_R2;
        const int nn = g >> 1;
        const bool posg = ((g & 1) == 0);
        for (u32 j = tid; j < c; j += 256) {
            const u32 key = aload(&list[(g * CAPL + j) * 2]);
            const u32 idx = aload(&list[(g * CAPL + j) * 2 + 1]);
            const u32 sbn = (key >> 11) & 1023u;
            if (sbn > usb) {
                const size_t o = (size_t)nn * KA + idx;
                patch1(&o32[5 * NK + o]);
                if (posg) patch1(&o32[6 * NK + o]);
            } else if (sbn == usb) {
                const u32 p = atomicAdd(&s_tc, 1u);
                if (p < 256) { tk[p] = key; ti[p] = idx; }
            }
        }
        __syncthreads();
        u32 tc = s_tc;
        if (tc > 256) tc = 256;
        // rank tiny tie set by (key desc, idx asc) — stable top_k semantics
        for (u32 i = tid; i < tc; i += 256) {
            const u32 ki = tk[i], ii = ti[i];
            u32 rank = 0;
            for (u32 j = 0; j < tc; ++j) {
                const u32 kj = tk[j];
                if (kj > ki || (kj == ki && ti[j] < ii)) rank++;
            }
            if (rank < R2) {
                const size_t o = (size_t)nn * KA + ii;
                patch1(&o32[5 * NK + o]);
                if (posg) patch1(&o32[6 * NK + o]);
            }
        }
        __syncthreads();
    }
}

extern "C" void kernel_launch(void* const* d_in, const int* in_sizes, int n_in,
                              void* d_out, int out_size, void* d_ws, size_t ws_size,
                              hipStream_t stream) {
    (void)in_sizes; (void)n_in; (void)out_size; (void)ws_size;
    const float4* anchors = (const float4*)d_in[0];   // (K,4) f32
    const float*  scores  = (const float*)d_in[1];    // (N,K) f32
    const float4* gtb     = (const float4*)d_in[2];   // (N,M,4) f32
    const int*    glab    = (const int*)d_in[3];      // (N,M) int32
    float* out = (float*)d_out;
    u32* ws = (u32*)d_ws;

    AnchorTargetLayer_48052094107725_kernel<<<GRID1, 256, 0, stream>>>(
        anchors, scores, gtb, glab, out, ws);
    kP<<<GRID1, 256, 0, stream>>>(scores, ws, out);
}